// Round 3
// baseline (67.399 us; speedup 1.0000x reference)
//
#include <hip/hip_runtime.h>

#define B_SZ 256
#define D_SZ 256
#define N_TOT 512   // 2*B

#define NBLK 64
#define NTHR 1024   // 16 waves -> 16 pairs/block; 64*16 = 1024 pairs
#define PREP_BLKS 16

#define MAGIC 0x3A9F17C5u   // arbitrary; cannot match a harness fill pattern by accident

// ---------------- workspace layout ----------------
// float  S1part[16][256] : float idx [0, 4096)
// float  S2part[16][256] : float idx [4096, 8192)
// u32    flag1[16]       : byte 32768   (prep-done flags, write-once to MAGIC)
// double lossPart[64]    : byte 33024
// u32    flag2[64]       : byte 33536   (loss-done flags)
// No slot needs pre-zeroing: all cross-block signalling is write-once magic
// flags, so the per-iteration ws poison is harmless.

// ---------------------------------------------------------------------------
// Single fused kernel, 64 blocks x 1024 threads.
//  1. Phase-B prework (bw-independent) for all blocks: float4 row loads,
//     diffs, wave inclusive scan of the feature-axis cumsum.
//  2. Blocks 0..15: non-redundant column partial sums (identical grouping
//     and f32 chain order to the previous prep_kernel -> bit-identical bw),
//     publish S1part/S2part + release MAGIC flag.
//  3. All blocks spin on the 16 flags (co-residency guaranteed: 64 blocks,
//     16 waves + 8KB LDS each, on 256 CUs; every block writes its flags
//     BEFORE spinning so there is no wait cycle).
//  4. bw combine (tx<256, f64), 5-bandwidth Gaussian sum, signed f64
//     wave/block reduce -> lossPart[bid] + release MAGIC flag2.
//  5. Block 0 wave 0: per-lane spin on flag2[lane], acquire, load the 64
//     partials, deterministic shfl-tree f64 reduce, write out.
// ---------------------------------------------------------------------------
__global__ __launch_bounds__(NTHR) void mmd_kernel(const float* __restrict__ src,
                                                   const float* __restrict__ tgt,
                                                   void* __restrict__ ws,
                                                   float* __restrict__ out) {
    const int tx   = threadIdx.x;
    const int lane = tx & 63;
    const int wave = tx >> 6;                   // 0..15
    const int bid  = blockIdx.x;

    float*    wsf      = (float*)ws;
    unsigned* flag1    = (unsigned*)((char*)ws + 32768);
    double*   lossPart = (double*)((char*)ws + 33024);
    unsigned* flag2    = (unsigned*)((char*)ws + 33536);

    // ---- 1. Phase-B prework ----
    const int wid = bid * 16 + wave;            // 0..1023
    const int p   = wid & 255;
    const int t   = wid >> 8;
    const int q   = (p + 1) & 255;

    const float* rowA;
    const float* rowB;
    double sign;
    if (t == 0)      { rowA = src + p * D_SZ; rowB = src + q * D_SZ; sign =  1.0; }
    else if (t == 1) { rowA = tgt + p * D_SZ; rowB = tgt + q * D_SZ; sign =  1.0; }
    else if (t == 2) { rowA = src + p * D_SZ; rowB = tgt + q * D_SZ; sign = -1.0; }
    else             { rowA = src + q * D_SZ; rowB = tgt + p * D_SZ; sign = -1.0; }

    float4 a4 = ((const float4*)rowA)[lane];
    float4 b4 = ((const float4*)rowB)[lane];
    float d0 = a4.x - b4.x, d1 = a4.y - b4.y, d2 = a4.z - b4.z, d3 = a4.w - b4.w;
    float c0 = d0 * d0;
    float c1 = c0 + d1 * d1;
    float c2 = c1 + d2 * d2;
    float c3 = c2 + d3 * d3;

    float s = c3;
    #pragma unroll
    for (int off = 1; off < 64; off <<= 1) {
        float v = __shfl_up(s, off, 64);
        if (lane >= off) s += v;
    }
    float prefix = __shfl_up(s, 1, 64);
    if (lane == 0) prefix = 0.f;

    float cum0 = prefix + c0;
    float cum1 = prefix + c1;
    float cum2 = prefix + c2;
    float cum3 = prefix + c3;

    // ---- 2. prep: blocks 0..15 publish column partial sums ----
    __shared__ float sh1[4][D_SZ];
    __shared__ float sh2[4][D_SZ];
    if (bid < PREP_BLKS) {
        const int col  = tx & 255;
        const int grp  = tx >> 8;               // 0..3
        const int row0 = bid * 32 + grp * 8;    // 0..504, never straddles halves
        const float* ptr = (row0 < B_SZ ? src + row0 * D_SZ
                                        : tgt + (row0 - B_SZ) * D_SZ) + col;
        float s1 = 0.f, s2 = 0.f;
        #pragma unroll
        for (int i = 0; i < 8; ++i) {
            float a = ptr[i * D_SZ];
            s1 += a;
            s2 = fmaf(a, a, s2);
        }
        sh1[grp][col] = s1;
        sh2[grp][col] = s2;
        __syncthreads();
        if (tx < 256) {
            wsf[bid * 256 + tx] =
                sh1[0][tx] + sh1[1][tx] + sh1[2][tx] + sh1[3][tx];
            wsf[4096 + bid * 256 + tx] =
                sh2[0][tx] + sh2[1][tx] + sh2[2][tx] + sh2[3][tx];
        }
        __syncthreads();
        if (tx == 0) {
            __threadfence();
            __hip_atomic_store(&flag1[bid], MAGIC, __ATOMIC_RELEASE,
                               __HIP_MEMORY_SCOPE_AGENT);
        }
    }

    // ---- 3. wait for all prep partials ----
    if (tx < PREP_BLKS) {
        while (__hip_atomic_load(&flag1[tx], __ATOMIC_ACQUIRE,
                                 __HIP_MEMORY_SCOPE_AGENT) != MAGIC)
            __builtin_amdgcn_s_sleep(2);
    }
    __syncthreads();

    // ---- 4a. bandwidth combine (waves 0..3) ----
    __shared__ double shred[4];
    __shared__ double sh_bw;
    if (tx < 256) {
        // per-thread acquire so this thread's subsequent plain loads see the
        // published partials (cache-invalidate on this CU)
        (void)__hip_atomic_load(&flag1[0], __ATOMIC_ACQUIRE,
                                __HIP_MEMORY_SCOPE_AGENT);
        double S1 = 0.0, S2 = 0.0;
        #pragma unroll
        for (int b = 0; b < 16; ++b) {
            S1 += (double)wsf[b * 256 + tx];
            S2 += (double)wsf[4096 + b * 256 + tx];
        }
        double pairsum = 2.0 * (double)N_TOT * S2 - 2.0 * S1 * S1;
        double local   = (double)(D_SZ - tx) * pairsum;
        #pragma unroll
        for (int off = 32; off > 0; off >>= 1)
            local += __shfl_down(local, off, 64);
        if (lane == 0) shred[wave] = local;
    }
    __syncthreads();
    if (tx == 0) {
        double total = shred[0] + shred[1] + shred[2] + shred[3];
        // bandwidth = total/(n^2-n) / (kernel_mul^(num/2)) = total/(n^2-n)/4
        sh_bw = total / ((double)N_TOT * (double)(N_TOT - 1)) * 0.25;
    }
    __syncthreads();
    const float bw = (float)sh_bw;

    // ---- 4b. multi-kernel Gaussian sum + block reduce ----
    float acc = 0.f;
    float inv = 1.0f / bw;
    #pragma unroll
    for (int k = 0; k < 5; ++k) {
        acc += expf(-cum0 * inv) + expf(-cum1 * inv) + expf(-cum2 * inv) + expf(-cum3 * inv);
        inv *= 0.5f;
    }

    double lacc = (double)acc * sign;
    #pragma unroll
    for (int off = 32; off > 0; off >>= 1)
        lacc += __shfl_down(lacc, off, 64);

    __shared__ double blk[16];
    if (lane == 0) blk[wave] = lacc;
    __syncthreads();
    if (tx == 0) {
        double bsum = 0.0;
        #pragma unroll
        for (int w = 0; w < 16; ++w) bsum += blk[w];
        lossPart[bid] = bsum;
        __threadfence();
        __hip_atomic_store(&flag2[bid], MAGIC, __ATOMIC_RELEASE,
                           __HIP_MEMORY_SCOPE_AGENT);
    }

    // ---- 5. block 0, wave 0: gather the 64 partials, write out ----
    if (bid == 0 && wave == 0) {
        while (__hip_atomic_load(&flag2[lane], __ATOMIC_ACQUIRE,
                                 __HIP_MEMORY_SCOPE_AGENT) != MAGIC)
            __builtin_amdgcn_s_sleep(2);
        double v = lossPart[lane];
        #pragma unroll
        for (int off = 32; off > 0; off >>= 1)
            v += __shfl_down(v, off, 64);
        if (lane == 0)
            out[0] = (float)(v * (1.0 / ((double)B_SZ * (double)D_SZ)));
    }
}

extern "C" void kernel_launch(void* const* d_in, const int* in_sizes, int n_in,
                              void* d_out, int out_size, void* d_ws, size_t ws_size,
                              hipStream_t stream) {
    const float* src = (const float*)d_in[0];
    const float* tgt = (const float*)d_in[1];
    float* out = (float*)d_out;

    mmd_kernel<<<NBLK, NTHR, 0, stream>>>(src, tgt, d_ws, out);
}

// Round 4
// 62.239 us; speedup vs baseline: 1.0829x; 1.0829x over previous
//
#include <hip/hip_runtime.h>

#define B_SZ 256
#define D_SZ 256
#define N_TOT 512   // 2*B

// ---------------- workspace layout (bytes) ----------------
// [0      , 16384)  : float S1part[16][256]
// [16384  , 32768)  : float S2part[16][256]
// [32768  , 32776)  : double acc   (signed loss accumulator)
// [32776  , 32780)  : unsigned cnt (blocks-done counter)
#define WS_S2_OFF   4096      // in floats
#define WS_ACC_OFF  32768     // in bytes
#define WS_CNT_OFF  32776     // in bytes

#define K1_BLK 16
#define K1_THR 1024
#define K2_BLK 128
#define K2_THR 512

// ---------------------------------------------------------------------------
// REVERT of the round-3 spin-flag fusion (regressed 62.2 -> 67.4 us: per-
// thread device-scope acquire loads + threadfence L2 writebacks + cross-XCD
// flag polling cost more than the kernel-edge dependency they replaced).
// This is the verified-best round-2 structure: two kernels, atomic finish.
//
// K1: non-redundant column partial sums + ws accumulator init.
// 16 blocks x 1024 threads. Block b owns rows [32b, 32b+32) of the 512
// concatenated rows (blocks 0-7 -> src, 8-15 -> tgt; never straddles).
// 1024 thr = 4 row-groups x 256 cols; each thread reads 8 strided values.
// LDS-combine the 4 groups -> S1part[b][col], S2part[b][col] (f32 stores).
// Block 0 thread 0 zeroes the acc/cnt slots (poisoned every iteration).
// ---------------------------------------------------------------------------
__global__ __launch_bounds__(K1_THR) void prep_kernel(const float* __restrict__ src,
                                                      const float* __restrict__ tgt,
                                                      void* __restrict__ ws) {
    const int tx  = threadIdx.x;
    const int col = tx & 255;
    const int grp = tx >> 8;                    // 0..3
    const int row0 = blockIdx.x * 32 + grp * 8; // 0..504

    const float* ptr = (row0 < B_SZ ? src + row0 * D_SZ
                                    : tgt + (row0 - B_SZ) * D_SZ) + col;
    float s1 = 0.f, s2 = 0.f;
    #pragma unroll
    for (int i = 0; i < 8; ++i) {
        float a = ptr[i * D_SZ];
        s1 += a;
        s2 = fmaf(a, a, s2);
    }

    __shared__ float sh1[4][D_SZ];
    __shared__ float sh2[4][D_SZ];
    sh1[grp][col] = s1;
    sh2[grp][col] = s2;
    __syncthreads();

    float* wsf = (float*)ws;
    if (tx < 256) {
        wsf[blockIdx.x * 256 + tx] =
            sh1[0][tx] + sh1[1][tx] + sh1[2][tx] + sh1[3][tx];
        wsf[WS_S2_OFF + blockIdx.x * 256 + tx] =
            sh2[0][tx] + sh2[1][tx] + sh2[2][tx] + sh2[3][tx];
    }
    if (blockIdx.x == 0 && tx == 0) {
        *(double*)((char*)ws + WS_ACC_OFF)   = 0.0;
        *(unsigned*)((char*)ws + WS_CNT_OFF) = 0u;
    }
}

// ---------------------------------------------------------------------------
// K2: 128 blocks x 512 threads (8 waves). Wave w -> pair wid = blockIdx*8+w
// (1024 pairs exactly: p = wid&255, type = wid>>8).
//   1. Phase-B prework (bw-independent): float4 row loads, diffs, wave
//      inclusive scan for the feature-axis cumsum.
//   2. Redundant-but-cheap bw combine: tx<256 sums the 16 f32 partials per
//      column in f64, weighted reduce -> bandwidth (identical formula).
//   3. 5-bandwidth Gaussian sum, signed f64 wave/block reduce.
//   4. Block partial -> f64 atomicAdd(acc); last block (counter) writes out.
// ---------------------------------------------------------------------------
__global__ __launch_bounds__(K2_THR) void main_kernel(const float* __restrict__ src,
                                                      const float* __restrict__ tgt,
                                                      void* __restrict__ ws,
                                                      float* __restrict__ out) {
    const int tx   = threadIdx.x;
    const int lane = tx & 63;
    const int wave = tx >> 6;                   // 0..7

    // ---- 1. Phase-B prework ----
    const int wid = blockIdx.x * 8 + wave;      // 0..1023
    const int p   = wid & 255;
    const int t   = wid >> 8;
    const int q   = (p + 1) & 255;

    const float* rowA;
    const float* rowB;
    double sign;
    if (t == 0)      { rowA = src + p * D_SZ; rowB = src + q * D_SZ; sign =  1.0; }
    else if (t == 1) { rowA = tgt + p * D_SZ; rowB = tgt + q * D_SZ; sign =  1.0; }
    else if (t == 2) { rowA = src + p * D_SZ; rowB = tgt + q * D_SZ; sign = -1.0; }
    else             { rowA = src + q * D_SZ; rowB = tgt + p * D_SZ; sign = -1.0; }

    float4 a4 = ((const float4*)rowA)[lane];
    float4 b4 = ((const float4*)rowB)[lane];
    float d0 = a4.x - b4.x, d1 = a4.y - b4.y, d2 = a4.z - b4.z, d3 = a4.w - b4.w;
    float c0 = d0 * d0;
    float c1 = c0 + d1 * d1;
    float c2 = c1 + d2 * d2;
    float c3 = c2 + d3 * d3;

    float s = c3;
    #pragma unroll
    for (int off = 1; off < 64; off <<= 1) {
        float v = __shfl_up(s, off, 64);
        if (lane >= off) s += v;
    }
    float prefix = __shfl_up(s, 1, 64);
    if (lane == 0) prefix = 0.f;

    float cum0 = prefix + c0;
    float cum1 = prefix + c1;
    float cum2 = prefix + c2;
    float cum3 = prefix + c3;

    // ---- 2. bandwidth combine (waves 0..3) ----
    __shared__ double shred[4];
    __shared__ double sh_bw;
    if (tx < 256) {
        const float* wsf = (const float*)ws;
        double S1 = 0.0, S2 = 0.0;
        #pragma unroll
        for (int b = 0; b < 16; ++b) {
            S1 += (double)wsf[b * 256 + tx];
            S2 += (double)wsf[WS_S2_OFF + b * 256 + tx];
        }
        double pairsum = 2.0 * (double)N_TOT * S2 - 2.0 * S1 * S1;
        double local   = (double)(D_SZ - tx) * pairsum;
        #pragma unroll
        for (int off = 32; off > 0; off >>= 1)
            local += __shfl_down(local, off, 64);
        if (lane == 0) shred[wave] = local;
    }
    __syncthreads();
    if (tx == 0) {
        double total = shred[0] + shred[1] + shred[2] + shred[3];
        // bandwidth = total/(n^2-n) / (kernel_mul^(num/2)) = total/(n^2-n)/4
        sh_bw = total / ((double)N_TOT * (double)(N_TOT - 1)) * 0.25;
    }
    __syncthreads();
    const float bw = (float)sh_bw;

    // ---- 3. multi-kernel Gaussian sum ----
    float acc = 0.f;
    float inv = 1.0f / bw;
    #pragma unroll
    for (int k = 0; k < 5; ++k) {
        acc += expf(-cum0 * inv) + expf(-cum1 * inv) + expf(-cum2 * inv) + expf(-cum3 * inv);
        inv *= 0.5f;
    }

    double lacc = (double)acc * sign;
    #pragma unroll
    for (int off = 32; off > 0; off >>= 1)
        lacc += __shfl_down(lacc, off, 64);

    __shared__ double blk[8];
    if (lane == 0) blk[wave] = lacc;
    __syncthreads();

    // ---- 4. cross-block combine via atomics (slots zeroed by K1) ----
    if (tx == 0) {
        double bsum = 0.0;
        #pragma unroll
        for (int w = 0; w < 8; ++w) bsum += blk[w];

        double*   accp = (double*)((char*)ws + WS_ACC_OFF);
        unsigned* cntp = (unsigned*)((char*)ws + WS_CNT_OFF);
        atomicAdd(accp, bsum);
        __threadfence();
        unsigned old = atomicAdd(cntp, 1u);
        if (old == K2_BLK - 1) {
            double total = __hip_atomic_load(accp, __ATOMIC_ACQUIRE,
                                             __HIP_MEMORY_SCOPE_AGENT);
            out[0] = (float)(total * (1.0 / ((double)B_SZ * (double)D_SZ)));
        }
    }
}

extern "C" void kernel_launch(void* const* d_in, const int* in_sizes, int n_in,
                              void* d_out, int out_size, void* d_ws, size_t ws_size,
                              hipStream_t stream) {
    const float* src = (const float*)d_in[0];
    const float* tgt = (const float*)d_in[1];
    float* out = (float*)d_out;

    prep_kernel<<<K1_BLK, K1_THR, 0, stream>>>(src, tgt, d_ws);
    main_kernel<<<K2_BLK, K2_THR, 0, stream>>>(src, tgt, d_ws, out);
}